// Round 1
// baseline (180.438 us; speedup 1.0000x reference)
//
#include <hip/hip_runtime.h>
#include <float.h>
#include <math.h>

#define NSAMP 100
#define IMG_W 2048
#define IMG_H 2048
#define LPP 4     // lanes cooperating per point
#define CPL 25    // minima-centers per lane (4*25 = 100 sample slots)

typedef _Float16 h2_t __attribute__((ext_vector_type(2), aligned(4)));
typedef _Float16 h4_t __attribute__((ext_vector_type(4), aligned(8)));
typedef _Float16 h8_t __attribute__((ext_vector_type(8), aligned(16)));

// Build vertical-pair fp16 texture: V[y][x] = (img[y][x], img[min(y+1,H-1)][x]).
// One thread converts 4 texels (reads float4 from rows y and y+1, writes 16 B).
// Thread 0 of block 0 also zeroes the accumulator state.
__global__ __launch_bounds__(256) void convert_kernel(const float* __restrict__ in,
                                                      h2_t* __restrict__ V,
                                                      double* __restrict__ accum,
                                                      unsigned int* __restrict__ done) {
    int idx = blockIdx.x * blockDim.x + threadIdx.x;   // 2048*512 threads
    if (idx == 0) { *accum = 0.0; *done = 0u; }
    int y  = idx >> 9;          // row 0..2047
    int x4 = (idx & 511) << 2;  // col 0,4,..,2044
    int y1 = min(y + 1, IMG_H - 1);
    float4 a = *(const float4*)(in + (size_t)y  * IMG_W + x4);
    float4 b = *(const float4*)(in + (size_t)y1 * IMG_W + x4);
    h8_t o;
    o[0] = (_Float16)a.x; o[1] = (_Float16)b.x;
    o[2] = (_Float16)a.y; o[3] = (_Float16)b.y;
    o[4] = (_Float16)a.z; o[5] = (_Float16)b.z;
    o[6] = (_Float16)a.w; o[7] = (_Float16)b.w;
    *(h8_t*)(V + (size_t)y * IMG_W + x4) = o;
}

// Bilinear via ONE 8-byte load: V[y0][xa], V[y0][xa+1] hold all 4 corners.
__device__ __forceinline__ float bilinV(const h2_t* __restrict__ V, float x, float y) {
    // x,y already clipped to [0, 2047]
    float x0f = floorf(x), y0f = floorf(y);
    float wx = x - x0f, wy = y - y0f;
    int x0 = (int)x0f;
    int y0 = (int)y0f;
    int xa = min(x0, IMG_W - 2);          // pair base; if x0==2047 shift left one
    bool edge = (x0 == IMG_W - 1);        // then wx==0, right-column weight is 0
    h4_t q = *(const h4_t*)(V + (size_t)y0 * IMG_W + xa);
    // q = (v00,v10, v01,v11) for columns xa, xa+1
    float v00 = edge ? (float)q[2] : (float)q[0];
    float v10 = edge ? (float)q[3] : (float)q[1];
    float v01 = (float)q[2];
    float v11 = (float)q[3];
    return v00 * (1.f - wx) * (1.f - wy) + v01 * wx * (1.f - wy)
         + v10 * (1.f - wx) * wy       + v11 * wx * wy;
}

__device__ __forceinline__ float tparam(int s) {
    // matches np.linspace(0,1,100), bitwise-verified in rounds 1-6
    return (s == NSAMP - 1) ? 1.0f : (float)((double)s * (1.0 / 99.0));
}

// 4 lanes per point: lane k owns minima-centers c in [25k, 25k+24] ∩ [1, 98].
// Each lane computes 27 bilinear samples (its 25 slots + 2 boundary neighbors),
// finds its best (d2, idx, val), then a 4-lane xor-butterfly min-reduce with
// index tie-break reproduces argmin's first-index semantics exactly.
__global__ __launch_bounds__(256) void contour_loss_kernel(
        const h2_t* __restrict__ V,
        const float* __restrict__ points,
        const float* __restrict__ normals,
        double* __restrict__ accum,
        unsigned int* __restrict__ done,
        float* __restrict__ out,
        int N, int nblocks) {
    int tid = blockIdx.x * blockDim.x + threadIdx.x;
    int p = tid >> 2;        // point index
    int k = tid & 3;         // lane-within-point
    float sq = 0.f;
    if (p < N) {
        float2 pt = *(const float2*)(points  + 2 * (size_t)p);
        float2 nm = *(const float2*)(normals + 2 * (size_t)p);
        float px = fminf(fmaxf(pt.x, 0.f), 2047.f);
        float py = fminf(fmaxf(pt.y, 0.f), 2047.f);
        float ddx = -nm.y, ddy = nm.x;
        float nrm = sqrtf(ddx * ddx + ddy * ddy);
        float dx = ddx / nrm, dy = ddy / nrm;

        const float maxf = FLT_MAX;
        float sdx = (dx != 0.f) ? dx : 1.f;
        float sdy = (dy != 0.f) ? dy : 1.f;
        float t_left   = (dx != 0.f) ? (0.f    - px) / sdx : -maxf;
        float t_right  = (dx != 0.f) ? (2047.f - px) / sdx :  maxf;
        float t_top    = (dy != 0.f) ? (0.f    - py) / sdy : -maxf;
        float t_bottom = (dy != 0.f) ? (2047.f - py) / sdy :  maxf;
        float t_min = fmaxf(t_left, t_top);
        float t_max = fminf(t_right, t_bottom);

        float p1x = px + t_min * dx, p1y = py + t_min * dy;
        float p2x = px + t_max * dx, p2y = py + t_max * dy;
        float vx = p2x - p1x, vy = p2y - p1y;

        float ref_val = bilinV(V, px, py);   // same addr for all 4 lanes: L1 hit

        int cbase = k * CPL;                 // first center slot for this lane
        // rolling window: v_im1 = sample(cbase-1), v_i = sample(cbase)
        int sm1 = cbase - 1; if (sm1 < 0) sm1 = 0;   // c=0 is masked anyway
        float ts = tparam(sm1);
        float blx = fminf(fmaxf(p1x + ts * vx, 0.f), 2047.f);
        float bly = fminf(fmaxf(p1y + ts * vy, 0.f), 2047.f);
        float v_im1 = bilinV(V, blx, bly);
        ts = tparam(cbase);
        float cx = fminf(fmaxf(p1x + ts * vx, 0.f), 2047.f);
        float cy = fminf(fmaxf(p1y + ts * vy, 0.f), 2047.f);
        float v_i = bilinV(V, cx, cy);

        float best_val = 0.f;
        float best_d2  = INFINITY;
        int   best_idx = 0x7FFFFFFF;
        float val_s1   = 0.f;    // vals[1] fallback (argmin of all-inf == 0)

        #pragma unroll 5
        for (int j = 0; j < CPL; ++j) {
            int c = cbase + j;
            int sn = c + 1; if (sn > NSAMP - 1) sn = NSAMP - 1;  // c=99 masked
            float tsn = tparam(sn);
            float nlx = fminf(fmaxf(p1x + tsn * vx, 0.f), 2047.f);
            float nly = fminf(fmaxf(p1y + tsn * vy, 0.f), 2047.f);
            float v_ip1 = bilinV(V, nlx, nly);
            if (c == 1) val_s1 = v_i;        // only ever true on lane 0
            if (c >= 1 && c <= NSAMP - 2 && v_i < v_im1 && v_i < v_ip1) {
                float ex = cx - px, ey = cy - py;
                float d2 = ex * ex + ey * ey;
                if (d2 < best_d2) { best_d2 = d2; best_val = v_i; best_idx = c; }
            }
            v_im1 = v_i; v_i = v_ip1; cx = nlx; cy = nly;
        }

        // 4-lane argmin reduce (xor butterfly), tie-break on lower sample index
        #pragma unroll
        for (int m = 1; m < LPP; m <<= 1) {
            float od2  = __shfl_xor(best_d2, m);
            float oval = __shfl_xor(best_val, m);
            int   oidx = __shfl_xor(best_idx, m);
            if (od2 < best_d2 || (od2 == best_d2 && oidx < best_idx)) {
                best_d2 = od2; best_val = oval; best_idx = oidx;
            }
        }

        if (k == 0) {
            if (best_idx == 0x7FFFFFFF) best_val = val_s1;  // no minima found
            float diff = best_val - ref_val;
            sq = diff * diff;
        }
    }

    // wave (64-lane) shuffle reduction
    for (int off = 32; off > 0; off >>= 1)
        sq += __shfl_down(sq, off);
    __shared__ float wsum[4];
    int lane = threadIdx.x & 63;
    int wid  = threadIdx.x >> 6;
    if (lane == 0) wsum[wid] = sq;
    __syncthreads();
    if (threadIdx.x == 0) {
        float bs = wsum[0] + wsum[1] + wsum[2] + wsum[3];
        atomicAdd(accum, (double)bs);
        __threadfence();
        unsigned int prev = atomicAdd(done, 1u);
        if (prev == (unsigned int)(nblocks - 1)) {
            double total = atomicAdd(accum, 0.0);  // device-scope coherent read
            out[0] = (float)(total / (double)N);
        }
    }
}

extern "C" void kernel_launch(void* const* d_in, const int* in_sizes, int n_in,
                              void* d_out, int out_size, void* d_ws, size_t ws_size,
                              hipStream_t stream) {
    const float* img     = (const float*)d_in[0];
    const float* points  = (const float*)d_in[1];
    const float* normals = (const float*)d_in[2];
    int N = in_sizes[1] / 2;
    float* out = (float*)d_out;

    // d_ws layout: [0, 16 MiB) vertical-pair fp16 texture; then accum; then done
    char* ws = (char*)d_ws;
    h2_t* V = (h2_t*)ws;
    size_t off = (size_t)IMG_W * IMG_H * sizeof(h2_t);   // 16 MiB
    double* accum      = (double*)(ws + off);  off += 8;
    unsigned int* done = (unsigned int*)(ws + off);

    int conv_blocks = (IMG_W * IMG_H / 4) / 256;   // 4 texels per thread
    convert_kernel<<<conv_blocks, 256, 0, stream>>>(img, V, accum, done);

    int grid = (4 * N + 255) / 256;                // 4 lanes per point
    contour_loss_kernel<<<grid, 256, 0, stream>>>(V, points, normals,
                                                  accum, done, out, N, grid);
}

// Round 2
// 155.606 us; speedup vs baseline: 1.1596x; 1.1596x over previous
//
#include <hip/hip_runtime.h>
#include <float.h>
#include <math.h>

#define NSAMP 100
#define IMG_W 2048
#define IMG_H 2048

typedef _Float16 h4w_t __attribute__((ext_vector_type(4), aligned(8)));   // aligned 8B store
typedef _Float16 h4r_t __attribute__((ext_vector_type(4), aligned(4)));   // 4B-aligned 8B load

// Build plain fp16 texture T[y][x] = (half)img[y][x]  (8 MB, no redundancy).
// One thread converts 4 texels (reads float4, writes 8 B).
// Thread 0 also zeroes the accumulator state.
__global__ __launch_bounds__(256) void convert_kernel(const float* __restrict__ in,
                                                      _Float16* __restrict__ T,
                                                      double* __restrict__ accum,
                                                      unsigned int* __restrict__ done) {
    int idx = blockIdx.x * blockDim.x + threadIdx.x;   // 2048*512 threads
    if (idx == 0) { *accum = 0.0; *done = 0u; }
    int y  = idx >> 9;          // row 0..2047
    int x4 = (idx & 511) << 2;  // col 0,4,..,2044
    float4 a = *(const float4*)(in + (size_t)y * IMG_W + x4);
    h4w_t o;
    o[0] = (_Float16)a.x; o[1] = (_Float16)a.y;
    o[2] = (_Float16)a.z; o[3] = (_Float16)a.w;
    *(h4w_t*)(T + (size_t)y * IMG_W + x4) = o;
}

// Bilinear from plain fp16 texture: two 8-byte row loads at even-column base.
// Base xa = x0 & ~1 covers texels xa..xa+3, which always contains {x0, min(x0+1,2047)}.
// (xa=2046 on the last row reads 4 B past the 8 MB texture; workspace layout
//  leaves that slack before accum.)
__device__ __forceinline__ float bilinT(const _Float16* __restrict__ T, float x, float y) {
    // x,y already clipped to [0, 2047]
    float x0f = floorf(x), y0f = floorf(y);
    float wx = x - x0f, wy = y - y0f;
    int x0 = (int)x0f;
    int y0 = (int)y0f;
    int y1 = min(y0 + 1, IMG_H - 1);
    int xa = x0 & ~1;
    bool odd  = (x0 & 1) != 0;
    bool edge = (x0 == IMG_W - 1);        // then x1==x0, wx==0
    h4r_t r0 = *(const h4r_t*)(T + (y0 << 11) + xa);
    h4r_t r1 = *(const h4r_t*)(T + (y1 << 11) + xa);
    float v00 = odd ? (float)r0[1] : (float)r0[0];
    float v10 = odd ? (float)r1[1] : (float)r1[0];
    float v01 = edge ? (float)r0[1] : (odd ? (float)r0[2] : (float)r0[1]);
    float v11 = edge ? (float)r1[1] : (odd ? (float)r1[2] : (float)r1[1]);
    return v00 * (1.f - wx) * (1.f - wy) + v01 * wx * (1.f - wy)
         + v10 * (1.f - wx) * wy       + v11 * wx * wy;
}

__device__ __forceinline__ float tparam(int s) {
    // matches np.linspace(0,1,100), bitwise-verified in earlier rounds
    return (s == NSAMP - 1) ? 1.0f : (float)((double)s * (1.0 / 99.0));
}

__global__ __launch_bounds__(256) void contour_loss_kernel(
        const _Float16* __restrict__ T,
        const float* __restrict__ points,
        const float* __restrict__ normals,
        double* __restrict__ accum,
        unsigned int* __restrict__ done,
        float* __restrict__ out,
        int N, int nblocks) {
    int i = blockIdx.x * blockDim.x + threadIdx.x;
    float sq = 0.f;
    if (i < N) {
        float2 pt = *(const float2*)(points  + 2 * (size_t)i);
        float2 nm = *(const float2*)(normals + 2 * (size_t)i);
        float px = fminf(fmaxf(pt.x, 0.f), 2047.f);
        float py = fminf(fmaxf(pt.y, 0.f), 2047.f);
        float ddx = -nm.y, ddy = nm.x;
        float nrm = sqrtf(ddx * ddx + ddy * ddy);
        float dx = ddx / nrm, dy = ddy / nrm;

        const float maxf = FLT_MAX;
        float sdx = (dx != 0.f) ? dx : 1.f;
        float sdy = (dy != 0.f) ? dy : 1.f;
        float t_left   = (dx != 0.f) ? (0.f    - px) / sdx : -maxf;
        float t_right  = (dx != 0.f) ? (2047.f - px) / sdx :  maxf;
        float t_top    = (dy != 0.f) ? (0.f    - py) / sdy : -maxf;
        float t_bottom = (dy != 0.f) ? (2047.f - py) / sdy :  maxf;
        float t_min = fmaxf(t_left, t_top);
        float t_max = fminf(t_right, t_bottom);

        float p1x = px + t_min * dx, p1y = py + t_min * dy;
        float p2x = px + t_max * dx, p2y = py + t_max * dy;
        float vx = p2x - p1x, vy = p2y - p1y;

        float ref_val = bilinT(T, px, py);

        // sample s=0
        float lx = fminf(fmaxf(p1x, 0.f), 2047.f);
        float ly = fminf(fmaxf(p1y, 0.f), 2047.f);
        float v_im1 = bilinT(T, lx, ly);
        // sample s=1
        float t1 = tparam(1);
        lx = fminf(fmaxf(p1x + t1 * vx, 0.f), 2047.f);
        ly = fminf(fmaxf(p1y + t1 * vy, 0.f), 2047.f);
        float v_i = bilinT(T, lx, ly);
        float cx = lx, cy = ly;

        float best_val = v_i;     // argmin(all-inf)==0 -> vals[1]
        float best_d2  = INFINITY;

        #pragma unroll 8
        for (int s = 2; s < NSAMP; ++s) {
            float ts = tparam(s);
            float nlx = fminf(fmaxf(p1x + ts * vx, 0.f), 2047.f);
            float nly = fminf(fmaxf(p1y + ts * vy, 0.f), 2047.f);
            float v_ip1 = bilinT(T, nlx, nly);
            if (v_i < v_im1 && v_i < v_ip1) {
                float ex = cx - px, ey = cy - py;
                float d2 = ex * ex + ey * ey;
                if (d2 < best_d2) { best_d2 = d2; best_val = v_i; }
            }
            v_im1 = v_i; v_i = v_ip1; cx = nlx; cy = nly;
        }
        float diff = best_val - ref_val;
        sq = diff * diff;
    }

    // wave (64-lane) shuffle reduction
    for (int off = 32; off > 0; off >>= 1)
        sq += __shfl_down(sq, off);
    __shared__ float wsum[4];
    int lane = threadIdx.x & 63;
    int wid  = threadIdx.x >> 6;
    if (lane == 0) wsum[wid] = sq;
    __syncthreads();
    if (threadIdx.x == 0) {
        float bs = wsum[0] + wsum[1] + wsum[2] + wsum[3];
        atomicAdd(accum, (double)bs);
        __threadfence();
        unsigned int prev = atomicAdd(done, 1u);
        if (prev == (unsigned int)(nblocks - 1)) {
            double total = atomicAdd(accum, 0.0);  // device-scope coherent read
            out[0] = (float)(total / (double)N);
        }
    }
}

extern "C" void kernel_launch(void* const* d_in, const int* in_sizes, int n_in,
                              void* d_out, int out_size, void* d_ws, size_t ws_size,
                              hipStream_t stream) {
    const float* img     = (const float*)d_in[0];
    const float* points  = (const float*)d_in[1];
    const float* normals = (const float*)d_in[2];
    int N = in_sizes[1] / 2;
    float* out = (float*)d_out;

    // d_ws layout: [0, 8 MiB) fp16 texture; slack; accum/done at +16 MiB
    char* ws = (char*)d_ws;
    _Float16* T = (_Float16*)ws;
    size_t off = (size_t)16 * 1024 * 1024;
    double* accum      = (double*)(ws + off);  off += 8;
    unsigned int* done = (unsigned int*)(ws + off);

    int conv_blocks = (IMG_W * IMG_H / 4) / 256;   // 4 texels per thread
    convert_kernel<<<conv_blocks, 256, 0, stream>>>(img, T, accum, done);

    int grid = (N + 255) / 256;                    // 1 thread per point
    contour_loss_kernel<<<grid, 256, 0, stream>>>(T, points, normals,
                                                  accum, done, out, N, grid);
}

// Round 3
// 147.460 us; speedup vs baseline: 1.2236x; 1.0552x over previous
//
#include <hip/hip_runtime.h>
#include <float.h>
#include <math.h>

#define NSAMP 100
#define IMG_W 2048
#define IMG_H 2048
#define NSLOT 8          // padded accumulator slots (one 128B line apart)
#define SLOT_STRIDE 16   // doubles per slot stride (128 B)

typedef _Float16 h2_t __attribute__((ext_vector_type(2), aligned(4)));
typedef _Float16 h4_t __attribute__((ext_vector_type(4), aligned(8)));
typedef _Float16 h8_t __attribute__((ext_vector_type(8), aligned(16)));

// Build vertical-pair fp16 texture: V[y][x] = (img[y][x], img[min(y+1,H-1)][x]).
// One thread converts 4 texels (reads float4 from rows y and y+1, writes 16 B).
// Thread 0 of block 0 also zeroes the accumulator state.
__global__ __launch_bounds__(256) void convert_kernel(const float* __restrict__ in,
                                                      h2_t* __restrict__ V,
                                                      double* __restrict__ accum,
                                                      unsigned int* __restrict__ done) {
    int idx = blockIdx.x * blockDim.x + threadIdx.x;   // 2048*512 threads
    if (idx == 0) {
        #pragma unroll
        for (int s = 0; s < NSLOT; ++s) accum[s * SLOT_STRIDE] = 0.0;
        *done = 0u;
    }
    int y  = idx >> 9;          // row 0..2047
    int x4 = (idx & 511) << 2;  // col 0,4,..,2044
    int y1 = min(y + 1, IMG_H - 1);
    float4 a = *(const float4*)(in + (size_t)y  * IMG_W + x4);
    float4 b = *(const float4*)(in + (size_t)y1 * IMG_W + x4);
    h8_t o;
    o[0] = (_Float16)a.x; o[1] = (_Float16)b.x;
    o[2] = (_Float16)a.y; o[3] = (_Float16)b.y;
    o[4] = (_Float16)a.z; o[5] = (_Float16)b.z;
    o[6] = (_Float16)a.w; o[7] = (_Float16)b.w;
    *(h8_t*)(V + (size_t)y * IMG_W + x4) = o;
}

// Bilinear via ONE 8-byte load: V[y0][xa], V[y0][xa+1] hold all 4 corners.
__device__ __forceinline__ float bilinV(const h2_t* __restrict__ V, float x, float y) {
    // x,y already clipped to [0, 2047]
    float x0f = floorf(x), y0f = floorf(y);
    float wx = x - x0f, wy = y - y0f;
    int x0 = (int)x0f;
    int y0 = (int)y0f;
    int xa = min(x0, IMG_W - 2);          // pair base; if x0==2047 shift left one
    bool edge = (x0 == IMG_W - 1);        // then wx==0, right-column weight is 0
    h4_t q = *(const h4_t*)(V + (y0 << 11) + xa);
    // q = (v00,v10, v01,v11) for columns xa, xa+1
    float v00 = edge ? (float)q[2] : (float)q[0];
    float v10 = edge ? (float)q[3] : (float)q[1];
    float v01 = (float)q[2];
    float v11 = (float)q[3];
    return v00 * (1.f - wx) * (1.f - wy) + v01 * wx * (1.f - wy)
         + v10 * (1.f - wx) * wy       + v11 * wx * wy;
}

__device__ __forceinline__ float tparam(int s) {
    // matches np.linspace(0,1,100), bitwise-verified in earlier rounds
    return (s == NSAMP - 1) ? 1.0f : (float)((double)s * (1.0 / 99.0));
}

// One thread per point; 64-thread (single-wave) blocks for fine-grained CU
// load balance (1563 blocks over 256 CUs vs 391 coarse blocks).
__global__ __launch_bounds__(64) void contour_loss_kernel(
        const h2_t* __restrict__ V,
        const float* __restrict__ points,
        const float* __restrict__ normals,
        double* __restrict__ accum,
        unsigned int* __restrict__ done,
        float* __restrict__ out,
        int N, int nblocks) {
    int i = blockIdx.x * blockDim.x + threadIdx.x;
    float sq = 0.f;
    if (i < N) {
        float2 pt = *(const float2*)(points  + 2 * (size_t)i);
        float2 nm = *(const float2*)(normals + 2 * (size_t)i);
        float px = fminf(fmaxf(pt.x, 0.f), 2047.f);
        float py = fminf(fmaxf(pt.y, 0.f), 2047.f);
        float ddx = -nm.y, ddy = nm.x;
        float nrm = sqrtf(ddx * ddx + ddy * ddy);
        float dx = ddx / nrm, dy = ddy / nrm;

        const float maxf = FLT_MAX;
        float sdx = (dx != 0.f) ? dx : 1.f;
        float sdy = (dy != 0.f) ? dy : 1.f;
        float t_left   = (dx != 0.f) ? (0.f    - px) / sdx : -maxf;
        float t_right  = (dx != 0.f) ? (2047.f - px) / sdx :  maxf;
        float t_top    = (dy != 0.f) ? (0.f    - py) / sdy : -maxf;
        float t_bottom = (dy != 0.f) ? (2047.f - py) / sdy :  maxf;
        float t_min = fmaxf(t_left, t_top);
        float t_max = fminf(t_right, t_bottom);

        float p1x = px + t_min * dx, p1y = py + t_min * dy;
        float p2x = px + t_max * dx, p2y = py + t_max * dy;
        float vx = p2x - p1x, vy = p2y - p1y;

        float ref_val = bilinV(V, px, py);

        // sample s=0
        float lx = fminf(fmaxf(p1x, 0.f), 2047.f);
        float ly = fminf(fmaxf(p1y, 0.f), 2047.f);
        float v_im1 = bilinV(V, lx, ly);
        // sample s=1
        float t1 = tparam(1);
        lx = fminf(fmaxf(p1x + t1 * vx, 0.f), 2047.f);
        ly = fminf(fmaxf(p1y + t1 * vy, 0.f), 2047.f);
        float v_i = bilinV(V, lx, ly);
        float cx = lx, cy = ly;

        float best_val = v_i;     // argmin(all-inf)==0 -> vals[1]
        float best_d2  = INFINITY;

        #pragma unroll 14
        for (int s = 2; s < NSAMP; ++s) {   // 98 iters = 7 x 14, no remainder
            float ts = tparam(s);
            float nlx = fminf(fmaxf(p1x + ts * vx, 0.f), 2047.f);
            float nly = fminf(fmaxf(p1y + ts * vy, 0.f), 2047.f);
            float v_ip1 = bilinV(V, nlx, nly);
            if (v_i < v_im1 && v_i < v_ip1) {
                float ex = cx - px, ey = cy - py;
                float d2 = ex * ex + ey * ey;
                if (d2 < best_d2) { best_d2 = d2; best_val = v_i; }
            }
            v_im1 = v_i; v_i = v_ip1; cx = nlx; cy = nly;
        }
        float diff = best_val - ref_val;
        sq = diff * diff;
    }

    // single-wave block: pure shuffle reduction, no LDS
    for (int off = 32; off > 0; off >>= 1)
        sq += __shfl_down(sq, off);
    if (threadIdx.x == 0) {
        // spread atomics across 8 cache-line-padded slots to avoid TCC
        // serialization on one line with 1563 blocks
        atomicAdd(&accum[(blockIdx.x & (NSLOT - 1)) * SLOT_STRIDE], (double)sq);
        __threadfence();
        unsigned int prev = atomicAdd(done, 1u);
        if (prev == (unsigned int)(nblocks - 1)) {
            double total = 0.0;
            #pragma unroll
            for (int s = 0; s < NSLOT; ++s)
                total += atomicAdd(&accum[s * SLOT_STRIDE], 0.0);  // coherent read
            out[0] = (float)(total / (double)N);
        }
    }
}

extern "C" void kernel_launch(void* const* d_in, const int* in_sizes, int n_in,
                              void* d_out, int out_size, void* d_ws, size_t ws_size,
                              hipStream_t stream) {
    const float* img     = (const float*)d_in[0];
    const float* points  = (const float*)d_in[1];
    const float* normals = (const float*)d_in[2];
    int N = in_sizes[1] / 2;
    float* out = (float*)d_out;

    // d_ws layout: [0, 16 MiB) vertical-pair fp16 texture; then 8 padded
    // accumulator slots (128 B apart); then done counter
    char* ws = (char*)d_ws;
    h2_t* V = (h2_t*)ws;
    size_t off = (size_t)IMG_W * IMG_H * sizeof(h2_t);   // 16 MiB
    double* accum      = (double*)(ws + off);  off += NSLOT * SLOT_STRIDE * sizeof(double);
    unsigned int* done = (unsigned int*)(ws + off);

    int conv_blocks = (IMG_W * IMG_H / 4) / 256;   // 4 texels per thread
    convert_kernel<<<conv_blocks, 256, 0, stream>>>(img, V, accum, done);

    int grid = (N + 63) / 64;                      // single-wave blocks
    contour_loss_kernel<<<grid, 64, 0, stream>>>(V, points, normals,
                                                 accum, done, out, N, grid);
}

// Round 4
// 138.684 us; speedup vs baseline: 1.3011x; 1.0633x over previous
//
#include <hip/hip_runtime.h>
#include <float.h>
#include <math.h>

#define NSAMP 100
#define IMG_W 2048
#define IMG_H 2048
#define B   10   // samples per batch
#define NB  10   // batches (B*NB == NSAMP)

typedef _Float16 h2_t __attribute__((ext_vector_type(2), aligned(4)));
typedef _Float16 h4_t __attribute__((ext_vector_type(4), aligned(8)));
typedef _Float16 h8_t __attribute__((ext_vector_type(8), aligned(16)));

// Build vertical-pair fp16 texture: V[y][x] = (img[y][x], img[min(y+1,H-1)][x]).
// One thread converts 4 texels (reads float4 from rows y and y+1, writes 16 B).
// Thread 0 of block 0 also zeroes the accumulator state.
__global__ __launch_bounds__(256) void convert_kernel(const float* __restrict__ in,
                                                      h2_t* __restrict__ V,
                                                      double* __restrict__ accum,
                                                      unsigned int* __restrict__ done) {
    int idx = blockIdx.x * blockDim.x + threadIdx.x;   // 2048*512 threads
    if (idx == 0) { *accum = 0.0; *done = 0u; }
    int y  = idx >> 9;          // row 0..2047
    int x4 = (idx & 511) << 2;  // col 0,4,..,2044
    int y1 = min(y + 1, IMG_H - 1);
    float4 a = *(const float4*)(in + (size_t)y  * IMG_W + x4);
    float4 b = *(const float4*)(in + (size_t)y1 * IMG_W + x4);
    h8_t o;
    o[0] = (_Float16)a.x; o[1] = (_Float16)b.x;
    o[2] = (_Float16)a.y; o[3] = (_Float16)b.y;
    o[4] = (_Float16)a.z; o[5] = (_Float16)b.z;
    o[6] = (_Float16)a.w; o[7] = (_Float16)b.w;
    *(h8_t*)(V + (size_t)y * IMG_W + x4) = o;
}

// Bilinear via ONE 8-byte load: V[y0][xa], V[y0][xa+1] hold all 4 corners.
__device__ __forceinline__ float bilinV(const h2_t* __restrict__ V, float x, float y) {
    float x0f = floorf(x), y0f = floorf(y);
    float wx = x - x0f, wy = y - y0f;
    int x0 = (int)x0f;
    int y0 = (int)y0f;
    int xa = min(x0, IMG_W - 2);
    bool edge = (x0 == IMG_W - 1);
    h4_t q = *(const h4_t*)(V + (y0 << 11) + xa);
    float v00 = edge ? (float)q[2] : (float)q[0];
    float v10 = edge ? (float)q[3] : (float)q[1];
    float v01 = (float)q[2];
    float v11 = (float)q[3];
    return v00 * (1.f - wx) * (1.f - wy) + v01 * wx * (1.f - wy)
         + v10 * (1.f - wx) * wy       + v11 * wx * wy;
}

__device__ __forceinline__ float tparam(int s) {
    // matches np.linspace(0,1,100), bitwise-verified in earlier rounds
    return (s == NSAMP - 1) ? 1.0f : (float)((double)s * (1.0 / 99.0));
}

// One thread per point. Software-pipelined sampling: loads are issued in
// batches of B into statically-indexed register buffers, staying 2 batches
// (20 loads) ahead of consumption. Coordinates are recomputed at consume
// time (cheap VALU) so only the 8 B loaded payloads stay live in VGPRs.
__global__ __launch_bounds__(256) void contour_loss_kernel(
        const h2_t* __restrict__ V,
        const float* __restrict__ points,
        const float* __restrict__ normals,
        double* __restrict__ accum,
        unsigned int* __restrict__ done,
        float* __restrict__ out,
        int N, int nblocks) {
    int i = blockIdx.x * blockDim.x + threadIdx.x;
    float sq = 0.f;
    if (i < N) {
        float2 pt = *(const float2*)(points  + 2 * (size_t)i);
        float2 nm = *(const float2*)(normals + 2 * (size_t)i);
        float px = fminf(fmaxf(pt.x, 0.f), 2047.f);
        float py = fminf(fmaxf(pt.y, 0.f), 2047.f);
        float ddx = -nm.y, ddy = nm.x;
        float nrm = sqrtf(ddx * ddx + ddy * ddy);
        float dx = ddx / nrm, dy = ddy / nrm;

        const float maxf = FLT_MAX;
        float sdx = (dx != 0.f) ? dx : 1.f;
        float sdy = (dy != 0.f) ? dy : 1.f;
        float t_left   = (dx != 0.f) ? (0.f    - px) / sdx : -maxf;
        float t_right  = (dx != 0.f) ? (2047.f - px) / sdx :  maxf;
        float t_top    = (dy != 0.f) ? (0.f    - py) / sdy : -maxf;
        float t_bottom = (dy != 0.f) ? (2047.f - py) / sdy :  maxf;
        float t_min = fmaxf(t_left, t_top);
        float t_max = fminf(t_right, t_bottom);

        float p1x = px + t_min * dx, p1y = py + t_min * dy;
        float p2x = px + t_max * dx, p2y = py + t_max * dy;
        float vx = p2x - p1x, vy = p2y - p1y;

        float ref_val = bilinV(V, px, py);

        // triple-buffered register batches; all indices static after unroll
        h4_t q[3][B];

        auto issue = [&](int s, int buf, int j) {
            float ts = tparam(s);                          // compile-time const
            float lx = fminf(fmaxf(p1x + ts * vx, 0.f), 2047.f);
            float ly = fminf(fmaxf(p1y + ts * vy, 0.f), 2047.f);
            int x0 = (int)floorf(lx);
            int y0 = (int)floorf(ly);
            int xa = min(x0, IMG_W - 2);
            q[buf][j] = *(const h4_t*)(V + (y0 << 11) + xa);
        };

        // rolling minima-scan state: v0 = v[s-1] at (cx,cy), vm1 = v[s-2]
        float vm1 = 0.f, v0 = 0.f, cx = 0.f, cy = 0.f;
        float best_val = 0.f;     // overwritten at s==1 (vals[1] fallback)
        float best_d2  = INFINITY;

        auto process = [&](int s, int buf, int j) {
            float ts = tparam(s);
            float lx = fminf(fmaxf(p1x + ts * vx, 0.f), 2047.f);
            float ly = fminf(fmaxf(p1y + ts * vy, 0.f), 2047.f);
            float x0f = floorf(lx), y0f = floorf(ly);
            float wx = lx - x0f, wy = ly - y0f;
            int x0 = (int)x0f;
            bool edge = (x0 == IMG_W - 1);     // then wx==0, right weight 0
            h4_t qq = q[buf][j];
            float v00 = edge ? (float)qq[2] : (float)qq[0];
            float v10 = edge ? (float)qq[3] : (float)qq[1];
            float v01 = (float)qq[2];
            float v11 = (float)qq[3];
            float vnew = v00 * (1.f - wx) * (1.f - wy) + v01 * wx * (1.f - wy)
                       + v10 * (1.f - wx) * wy       + v11 * wx * wy;
            if (s == 1) best_val = vnew;       // static after unroll
            if (s >= 2 && v0 < vm1 && v0 < vnew) {   // center c = s-1 in [1,98]
                float ex = cx - px, ey = cy - py;
                float d2 = ex * ex + ey * ey;
                if (d2 < best_d2) { best_d2 = d2; best_val = v0; }
            }
            vm1 = v0; v0 = vnew; cx = lx; cy = ly;
        };

        // prologue: 2 batches in flight
        #pragma unroll
        for (int j = 0; j < B; ++j) issue(j, 0, j);
        #pragma unroll
        for (int j = 0; j < B; ++j) issue(B + j, 1, j);

        #pragma unroll
        for (int b = 0; b < NB; ++b) {
            if (b + 2 < NB) {
                #pragma unroll
                for (int j = 0; j < B; ++j) issue((b + 2) * B + j, (b + 2) % 3, j);
            }
            #pragma unroll
            for (int j = 0; j < B; ++j) process(b * B + j, b % 3, j);
        }

        float diff = best_val - ref_val;
        sq = diff * diff;
    }

    // wave (64-lane) shuffle reduction
    for (int off = 32; off > 0; off >>= 1)
        sq += __shfl_down(sq, off);
    __shared__ float wsum[4];
    int lane = threadIdx.x & 63;
    int wid  = threadIdx.x >> 6;
    if (lane == 0) wsum[wid] = sq;
    __syncthreads();
    if (threadIdx.x == 0) {
        float bs = wsum[0] + wsum[1] + wsum[2] + wsum[3];
        atomicAdd(accum, (double)bs);
        __threadfence();
        unsigned int prev = atomicAdd(done, 1u);
        if (prev == (unsigned int)(nblocks - 1)) {
            double total = atomicAdd(accum, 0.0);  // device-scope coherent read
            out[0] = (float)(total / (double)N);
        }
    }
}

extern "C" void kernel_launch(void* const* d_in, const int* in_sizes, int n_in,
                              void* d_out, int out_size, void* d_ws, size_t ws_size,
                              hipStream_t stream) {
    const float* img     = (const float*)d_in[0];
    const float* points  = (const float*)d_in[1];
    const float* normals = (const float*)d_in[2];
    int N = in_sizes[1] / 2;
    float* out = (float*)d_out;

    // d_ws layout: [0, 16 MiB) vertical-pair fp16 texture; then accum; then done
    char* ws = (char*)d_ws;
    h2_t* V = (h2_t*)ws;
    size_t off = (size_t)IMG_W * IMG_H * sizeof(h2_t);   // 16 MiB
    double* accum      = (double*)(ws + off);  off += 8;
    unsigned int* done = (unsigned int*)(ws + off);

    int conv_blocks = (IMG_W * IMG_H / 4) / 256;   // 4 texels per thread
    convert_kernel<<<conv_blocks, 256, 0, stream>>>(img, V, accum, done);

    int grid = (N + 255) / 256;                    // 1 thread per point
    contour_loss_kernel<<<grid, 256, 0, stream>>>(V, points, normals,
                                                  accum, done, out, N, grid);
}